// Round 1
// baseline (404.943 us; speedup 1.0000x reference)
//
#include <hip/hip_runtime.h>
#include <stdint.h>

typedef unsigned char u8;
typedef unsigned short u16;
typedef int i32x4 __attribute__((ext_vector_type(4)));
typedef u8 u8x4 __attribute__((ext_vector_type(4)));

#define B_N   16
#define C_CH  128
#define O_CH  256
#define HW    56
#define PH    58
#define PW    72

#define GLOBAL_AS __attribute__((address_space(1)))
#define LDS_AS    __attribute__((address_space(3)))

__device__ __forceinline__ void glds16(const void* g, void* l) {
    __builtin_amdgcn_global_load_lds((const GLOBAL_AS void*)g, (LDS_AS void*)l, 16, 0, 0);
}

// ws layout (bytes)
#define XQ_OFF   0                       // u8 [16][58][8 cg][72 wp][16 c]  = 8,552,448
#define BW_OFF   8552448                 // u8 [18 st][256 o][64 c]         =   294,912
#define TC_OFF   (BW_OFF + 294912)       // int [16][58][72]                =   267,264
#define WS_OFF   (TC_OFF + 267264)       // int [256]

// ---------------------------------------------------------------------------
// fused prep (unchanged from verified baseline):
//  blocks [0,928):    quantize + pad + NCHW->[b][hp][cg][wp][c16] as shifted
//                     i8 (q^0x80 == q-128; pad = -128), plus channel-sum plane
//                     Tc[b][hp][wp] = sum_c (q-128).
//  blocks [928,1216): Bw[st=r*2+q][o][c64] = (u8)qw ^ 0x80 and
//                     Wsum[o] += sum(qw-128)  (Wsum pre-zeroed by memset).
// ---------------------------------------------------------------------------
__global__ __launch_bounds__(256) void prep(const float* __restrict__ x,
                                            const float* __restrict__ pcilt,
                                            u8* __restrict__ xq,
                                            u8* __restrict__ Bw,
                                            int* __restrict__ Tc,
                                            int* __restrict__ Wsum) {
    const int bx = blockIdx.x;
    const int tid = threadIdx.x;

    if (bx < PH * B_N) {
        __shared__ u16 Lt[C_CH][57];             // integer q in [0,255]
        const int hp = bx % PH;
        const int b = bx / PH;
        const int h = hp - 1;
        const bool interior = (unsigned)h < HW;

        if (interior) {
            const float* xr = x + ((size_t)b * C_CH * HW + h) * HW;
            for (int i = 0; i < 7; ++i) {        // 1792 float4 units = 128c x 14
                int u = i * 256 + tid;
                int c = u / 14, w4 = u % 14;
                float4 v = *(const float4*)(xr + (size_t)c * (HW * HW) + w4 * 4);
                Lt[c][w4 * 4 + 0] = (u16)(int)fminf(fmaxf(rintf(v.x * 255.0f), 0.0f), 255.0f);
                Lt[c][w4 * 4 + 1] = (u16)(int)fminf(fmaxf(rintf(v.y * 255.0f), 0.0f), 255.0f);
                Lt[c][w4 * 4 + 2] = (u16)(int)fminf(fmaxf(rintf(v.z * 255.0f), 0.0f), 255.0f);
                Lt[c][w4 * 4 + 3] = (u16)(int)fminf(fmaxf(rintf(v.w * 255.0f), 0.0f), 255.0f);
            }
        }
        __syncthreads();
        // write xq row for (b,hp): 8 cg x 72 wp x 16 c = 9216 B = 2304 dwords
        u8* dst = xq + (size_t)(b * PH + hp) * 9216;
        for (int j = 0; j < 9; ++j) {
            int u = j * 256 + tid;
            int d4 = u & 3;
            int wp = (u >> 2) % PW;
            int cg = u / (4 * PW);
            int w = wp - 1;
            u8x4 v;
            if (interior && (unsigned)w < HW) {
#pragma unroll
                for (int e = 0; e < 4; ++e)
                    v[e] = (u8)Lt[cg * 16 + d4 * 4 + e][w] ^ 0x80;
            } else {
                v = (u8x4){0x80, 0x80, 0x80, 0x80};
            }
            *(u8x4*)(dst + (size_t)u * 4) = v;
        }
        // channel-sum plane
        if (tid < PW) {
            int wp = tid, w = wp - 1;
            int s = -128 * C_CH;
            if (interior && (unsigned)w < HW) {
                for (int c = 0; c < C_CH; ++c) s += (int)Lt[c][w];
            }
            Tc[(b * PH + hp) * PW + wp] = s;
        }
    } else {
        int v = (bx - PH * B_N) * 256 + tid;     // 73728 dword units
        int cb4 = v & 15;
        int o   = (v >> 4) & 255;
        int q   = (v >> 12) & 1;
        int r   = v >> 13;
        u8x4 out4;
        int part = 0;
#pragma unroll
        for (int e = 0; e < 4; ++e) {
            int c = q * 64 + cb4 * 4 + e;
            float w = pcilt[((size_t)(o * C_CH + c) * 9 + r) * 256 + 1];
            int qi = (int)w;
            out4[e] = (u8)qi ^ 0x80;
            part += qi - 128;
        }
        *(u8x4*)(Bw + (size_t)v * 4) = out4;
        part += __shfl_down(part, 1);
        part += __shfl_down(part, 2);
        part += __shfl_down(part, 4);
        part += __shfl_down(part, 8);
        if ((tid & 15) == 0) atomicAdd(&Wsum[o], part);
    }
}

// ---------------------------------------------------------------------------
// conv as implicit GEMM, exact i8 (zero-point shifted):
//   ACC[o][m] = sum_k (w-128)(a-128)
//   out = ACC + 128*(Sa[m] + Wsum[o]) + 128^2*1152 + bias
// NEW SCHEDULE (T3 minimum 2-phase): double-buffered Is (2 x 8 KB) +
// register-double-buffered weight fragments. One barrier per K-stage
// (was two); next-stage glds16 + weight loads issue BEFORE the current
// stage's MFMA burst, so their latency hides under compute. The barrier's
// implicit vmcnt(0) drain guarantees the prefetch landed before the next
// compute phase reads it. Buffer b is rewritten only after the barrier
// that drained all waves' lgkm reads of b (safe).
// ---------------------------------------------------------------------------
__global__ __launch_bounds__(256) void conv_mfma(const u8* __restrict__ xq,
                                                 const u8* __restrict__ Bw,
                                                 const int* __restrict__ Tc,
                                                 const int* __restrict__ Wsum,
                                                 const float* __restrict__ bias,
                                                 float* __restrict__ out) {
    __shared__ __align__(16) u8 Is[2][4][128][16]; // [buf][cg16][m][c16]  16 KB
    __shared__ int Sa_l[2][64];                    // 512 B

    const int tid = threadIdx.x;
    const int o_blk = blockIdx.x * 128;
    const int h0 = blockIdx.y * 2;
    const int b = blockIdx.z;

    const int lane = tid & 63;
    const int wid = tid >> 6;
    const int wo = wid & 1;
    const int wm = wid >> 1;
    const int quad = lane >> 4;
    const int lrow = lane & 15;

    // ---- prologue: per-block Sa (activation zero-point correction) ----
    if (tid < 128) {
        const int rr = tid >> 6, w = tid & 63;
        int s = 0;
        if (w < HW) {
            const int* t = Tc + (b * PH + h0 + rr) * PW + w;
#pragma unroll
            for (int dh = 0; dh < 3; ++dh)
#pragma unroll
                for (int dw = 0; dw < 3; ++dw)
                    s += t[dh * PW + dw];
        }
        Sa_l[rr][w] = s;
    }

    i32x4 acc[4][4];
#pragma unroll
    for (int i = 0; i < 4; i++)
#pragma unroll
        for (int j = 0; j < 4; j++) acc[i][j] = (i32x4){0, 0, 0, 0};

    // staging: wave covers dh = wid&1, cg pair = (wid>>1)*2 + {0,1}
    const int sdh = wid & 1;
    const int scg = (wid >> 1) * 2;
    const u8* gbase = xq + (size_t)(b * PH + h0 + sdh) * 9216 + lane * 16;
    const u8* wl = Bw + (size_t)(o_blk + wo * 64 + lrow) * 64 + quad * 16;

    // stage st = r*2+q, r = kh*3+kw; issues this wave's 2 glds16 into buf
#define STAGE(bufidx, st) do {                                                  \
        const int r_ = (st) >> 1, q_ = (st) & 1;                                \
        const int kh_ = r_ / 3, kw_ = r_ % 3;                                   \
        _Pragma("unroll")                                                       \
        for (int cc = 0; cc < 2; ++cc) {                                        \
            const int cg_ = scg + cc;                                           \
            const u8* src_ = gbase + kh_ * 9216 + (q_ * 4 + cg_) * (PW * 16)    \
                             + kw_ * 16;                                        \
            glds16(src_, &Is[bufidx][cg_][sdh * 64][0]);                        \
        }                                                                       \
    } while (0)

#define LOADW(dst, st) do {                                                     \
        _Pragma("unroll")                                                       \
        for (int i_ = 0; i_ < 4; ++i_)                                          \
            dst[i_] = *(const i32x4*)(wl + (size_t)(st) * 16384 + i_ * 1024);   \
    } while (0)

#define COMPUTE(bufidx, af) do {                                                \
        i32x4 bfr_[4];                                                          \
        _Pragma("unroll")                                                       \
        for (int j_ = 0; j_ < 4; ++j_)                                          \
            bfr_[j_] = *(const i32x4*)&Is[bufidx][quad][wm * 64 + j_ * 16 + lrow][0]; \
        _Pragma("unroll")                                                       \
        for (int i_ = 0; i_ < 4; ++i_)                                          \
            _Pragma("unroll")                                                   \
            for (int j_ = 0; j_ < 4; ++j_)                                      \
                acc[i_][j_] = __builtin_amdgcn_mfma_i32_16x16x64_i8(            \
                    af[i_], bfr_[j_], acc[i_][j_], 0, 0, 0);                    \
    } while (0)

    i32x4 afA[4], afB[4];

    // prologue: stage 0 into buf0, weights 0 into afA
    STAGE(0, 0);
    LOADW(afA, 0);
    __syncthreads();   // vmcnt(0): stage-0 data landed; also covers Sa_l

    for (int t = 0; t < 8; ++t) {
        const int st1 = t * 2 + 1;
        // even phase: prefetch odd stage, compute even stage
        STAGE(1, st1);
        LOADW(afB, st1);
        COMPUTE(0, afA);
        __syncthreads(); // drains prefetch; all reads of buf0 done
        // odd phase: prefetch next even stage, compute odd stage
        STAGE(0, st1 + 1);
        LOADW(afA, st1 + 1);
        COMPUTE(1, afB);
        __syncthreads(); // drains prefetch; all reads of buf1 done
    }
    // tail: stages 16,17
    STAGE(1, 17);
    LOADW(afB, 17);
    COMPUTE(0, afA);
    __syncthreads();
    COMPUTE(1, afB);

#undef STAGE
#undef LOADW
#undef COMPUTE

    // ---- epilogue: D[row=o][col=m]; col=lane&15, row=quad*4+reg ----
    const int hh = h0 + wm;
    int sa_j[4];
#pragma unroll
    for (int j = 0; j < 4; ++j) {
        const int w = j * 16 + lrow;
        sa_j[j] = (w < HW) ? Sa_l[wm][w] : 0;
    }
#pragma unroll
    for (int i = 0; i < 4; i++) {
        const int obase = o_blk + wo * 64 + i * 16 + quad * 4;
#pragma unroll
        for (int rg = 0; rg < 4; ++rg) {
            const int o = obase + rg;
            const int wsum = Wsum[o];
            const float bs = bias[o];
#pragma unroll
            for (int j = 0; j < 4; ++j) {
                const int w = j * 16 + lrow;
                if (w < HW) {
                    int tot = acc[i][j][rg] + 128 * (sa_j[j] + wsum) + 18874368;
                    out[(((size_t)b * O_CH + o) * HW + hh) * HW + w] = (float)tot + bs;
                }
            }
        }
    }
}

extern "C" void kernel_launch(void* const* d_in, const int* in_sizes, int n_in,
                              void* d_out, int out_size, void* d_ws, size_t ws_size,
                              hipStream_t stream) {
    const float* x     = (const float*)d_in[0];
    const float* pcilt = (const float*)d_in[1];
    const float* bias  = (const float*)d_in[2];
    float* out = (float*)d_out;

    u8* ws = (u8*)d_ws;
    u8*  xq   = ws + XQ_OFF;
    u8*  Bw   = ws + BW_OFF;
    int* Tc   = (int*)(ws + TC_OFF);
    int* Wsum = (int*)(ws + WS_OFF);

    hipMemsetAsync(Wsum, 0, O_CH * sizeof(int), stream);
    prep<<<PH * B_N + 288, 256, 0, stream>>>(x, pcilt, xq, Bw, Tc, Wsum);
    conv_mfma<<<dim3(O_CH / 128, HW / 2, B_N), dim3(256), 0, stream>>>(xq, Bw, Tc, Wsum, bias, out);
}

// Round 2
// 403.320 us; speedup vs baseline: 1.0040x; 1.0040x over previous
//
#include <hip/hip_runtime.h>
#include <stdint.h>

typedef unsigned char u8;
typedef unsigned short u16;
typedef int i32x4 __attribute__((ext_vector_type(4)));
typedef u8 u8x4 __attribute__((ext_vector_type(4)));

#define B_N   16
#define C_CH  128
#define O_CH  256
#define HW    56
#define PH    58
#define PW    72

#define GLOBAL_AS __attribute__((address_space(1)))
#define LDS_AS    __attribute__((address_space(3)))

__device__ __forceinline__ void glds16(const void* g, void* l) {
    __builtin_amdgcn_global_load_lds((const GLOBAL_AS void*)g, (LDS_AS void*)l, 16, 0, 0);
}

// ws layout (bytes)
#define XQ_OFF   0                       // u8 [16][58][8 cg][72 wp][16 c]  = 8,552,448
#define BW_OFF   8552448                 // u8 [18 st][256 o][64 c]         =   294,912
#define TC_OFF   (BW_OFF + 294912)       // int [16][58][72]                =   267,264
#define WP_OFF   (TC_OFF + 267264)       // int [18 st][256 o]              =    18,432

// ---------------------------------------------------------------------------
// fused prep:
//  blocks [0,928):    quantize + pad + NCHW->[b][hp][cg][wp][c16] as shifted
//                     i8 (q^0x80 == q-128; pad = -128), plus channel-sum plane
//                     Tc[b][hp][wp] = sum_c (q-128).
//  blocks [928,1216): Bw[st=r*2+q][o][c64] = (u8)qw ^ 0x80 and
//                     Wpart[st][o] = sum_{c in this st's 64} (qw-128).
//                     Each (st,o) slot is written by exactly one 16-thread
//                     group -> plain store, no init, no atomics.
// ---------------------------------------------------------------------------
__global__ __launch_bounds__(256) void prep(const float* __restrict__ x,
                                            const float* __restrict__ pcilt,
                                            u8* __restrict__ xq,
                                            u8* __restrict__ Bw,
                                            int* __restrict__ Tc,
                                            int* __restrict__ Wpart) {
    const int bx = blockIdx.x;
    const int tid = threadIdx.x;

    if (bx < PH * B_N) {
        __shared__ u16 Lt[C_CH][57];             // integer q in [0,255]
        const int hp = bx % PH;
        const int b = bx / PH;
        const int h = hp - 1;
        const bool interior = (unsigned)h < HW;

        if (interior) {
            const float* xr = x + ((size_t)b * C_CH * HW + h) * HW;
            for (int i = 0; i < 7; ++i) {        // 1792 float4 units = 128c x 14
                int u = i * 256 + tid;
                int c = u / 14, w4 = u % 14;
                float4 v = *(const float4*)(xr + (size_t)c * (HW * HW) + w4 * 4);
                Lt[c][w4 * 4 + 0] = (u16)(int)fminf(fmaxf(rintf(v.x * 255.0f), 0.0f), 255.0f);
                Lt[c][w4 * 4 + 1] = (u16)(int)fminf(fmaxf(rintf(v.y * 255.0f), 0.0f), 255.0f);
                Lt[c][w4 * 4 + 2] = (u16)(int)fminf(fmaxf(rintf(v.z * 255.0f), 0.0f), 255.0f);
                Lt[c][w4 * 4 + 3] = (u16)(int)fminf(fmaxf(rintf(v.w * 255.0f), 0.0f), 255.0f);
            }
        }
        __syncthreads();
        // write xq row for (b,hp): 8 cg x 72 wp x 16 c = 9216 B = 2304 dwords
        u8* dst = xq + (size_t)(b * PH + hp) * 9216;
        for (int j = 0; j < 9; ++j) {
            int u = j * 256 + tid;
            int d4 = u & 3;
            int wp = (u >> 2) % PW;
            int cg = u / (4 * PW);
            int w = wp - 1;
            u8x4 v;
            if (interior && (unsigned)w < HW) {
#pragma unroll
                for (int e = 0; e < 4; ++e)
                    v[e] = (u8)Lt[cg * 16 + d4 * 4 + e][w] ^ 0x80;
            } else {
                v = (u8x4){0x80, 0x80, 0x80, 0x80};
            }
            *(u8x4*)(dst + (size_t)u * 4) = v;
        }
        // channel-sum plane
        if (tid < PW) {
            int wp = tid, w = wp - 1;
            int s = -128 * C_CH;
            if (interior && (unsigned)w < HW) {
                for (int c = 0; c < C_CH; ++c) s += (int)Lt[c][w];
            }
            Tc[(b * PH + hp) * PW + wp] = s;
        }
    } else {
        int v = (bx - PH * B_N) * 256 + tid;     // 73728 dword units
        int cb4 = v & 15;
        int o   = (v >> 4) & 255;
        int q   = (v >> 12) & 1;
        int r   = v >> 13;
        u8x4 out4;
        int part = 0;
#pragma unroll
        for (int e = 0; e < 4; ++e) {
            int c = q * 64 + cb4 * 4 + e;
            float w = pcilt[((size_t)(o * C_CH + c) * 9 + r) * 256 + 1];
            int qi = (int)w;
            out4[e] = (u8)qi ^ 0x80;
            part += qi - 128;
        }
        *(u8x4*)(Bw + (size_t)v * 4) = out4;
        part += __shfl_down(part, 1);
        part += __shfl_down(part, 2);
        part += __shfl_down(part, 4);
        part += __shfl_down(part, 8);
        if ((tid & 15) == 0) {
            const int st = v >> 12;              // r*2+q
            Wpart[st * 256 + o] = part;          // written exactly once
        }
    }
}

// ---------------------------------------------------------------------------
// conv as implicit GEMM, exact i8 (zero-point shifted):
//   ACC[o][m] = sum_k (w-128)(a-128)
//   out = ACC + 128*(Sa[m] + Wsum[o]) + 128^2*1152 + bias
// Double-buffered Is (2 x 8 KB) + register-double-buffered weights, one
// barrier per K-stage; next-stage loads issue before the current stage's
// MFMA burst. Prologue: tid<128 computes Sa (activation correction);
// tid>=128 reduces Wpart[18][o] -> Wsum_l (weight correction), both
// covered by the first barrier.
// ---------------------------------------------------------------------------
__global__ __launch_bounds__(256) void conv_mfma(const u8* __restrict__ xq,
                                                 const u8* __restrict__ Bw,
                                                 const int* __restrict__ Tc,
                                                 const int* __restrict__ Wpart,
                                                 const float* __restrict__ bias,
                                                 float* __restrict__ out) {
    __shared__ __align__(16) u8 Is[2][4][128][16]; // [buf][cg16][m][c16]  16 KB
    __shared__ int Sa_l[2][64];                    // 512 B
    __shared__ int Wsum_l[128];                    // 512 B

    const int tid = threadIdx.x;
    const int o_blk = blockIdx.x * 128;
    const int h0 = blockIdx.y * 2;
    const int b = blockIdx.z;

    const int lane = tid & 63;
    const int wid = tid >> 6;
    const int wo = wid & 1;
    const int wm = wid >> 1;
    const int quad = lane >> 4;
    const int lrow = lane & 15;

    // ---- prologue: Sa (tid<128) and Wsum (tid>=128) corrections ----
    if (tid < 128) {
        const int rr = tid >> 6, w = tid & 63;
        int s = 0;
        if (w < HW) {
            const int* t = Tc + (b * PH + h0 + rr) * PW + w;
#pragma unroll
            for (int dh = 0; dh < 3; ++dh)
#pragma unroll
                for (int dw = 0; dw < 3; ++dw)
                    s += t[dh * PW + dw];
        }
        Sa_l[rr][w] = s;
    } else {
        const int oo = tid - 128;                  // 0..127
        int s = 0;
#pragma unroll
        for (int st = 0; st < 18; ++st)
            s += Wpart[st * 256 + o_blk + oo];
        Wsum_l[oo] = s;
    }

    i32x4 acc[4][4];
#pragma unroll
    for (int i = 0; i < 4; i++)
#pragma unroll
        for (int j = 0; j < 4; j++) acc[i][j] = (i32x4){0, 0, 0, 0};

    // staging: wave covers dh = wid&1, cg pair = (wid>>1)*2 + {0,1}
    const int sdh = wid & 1;
    const int scg = (wid >> 1) * 2;
    const u8* gbase = xq + (size_t)(b * PH + h0 + sdh) * 9216 + lane * 16;
    const u8* wl = Bw + (size_t)(o_blk + wo * 64 + lrow) * 64 + quad * 16;

    // stage st = r*2+q, r = kh*3+kw; issues this wave's 2 glds16 into buf
#define STAGE(bufidx, st) do {                                                  \
        const int r_ = (st) >> 1, q_ = (st) & 1;                                \
        const int kh_ = r_ / 3, kw_ = r_ % 3;                                   \
        _Pragma("unroll")                                                       \
        for (int cc = 0; cc < 2; ++cc) {                                        \
            const int cg_ = scg + cc;                                           \
            const u8* src_ = gbase + kh_ * 9216 + (q_ * 4 + cg_) * (PW * 16)    \
                             + kw_ * 16;                                        \
            glds16(src_, &Is[bufidx][cg_][sdh * 64][0]);                        \
        }                                                                       \
    } while (0)

#define LOADW(dst, st) do {                                                     \
        _Pragma("unroll")                                                       \
        for (int i_ = 0; i_ < 4; ++i_)                                          \
            dst[i_] = *(const i32x4*)(wl + (size_t)(st) * 16384 + i_ * 1024);   \
    } while (0)

#define COMPUTE(bufidx, af) do {                                                \
        i32x4 bfr_[4];                                                          \
        _Pragma("unroll")                                                       \
        for (int j_ = 0; j_ < 4; ++j_)                                          \
            bfr_[j_] = *(const i32x4*)&Is[bufidx][quad][wm * 64 + j_ * 16 + lrow][0]; \
        _Pragma("unroll")                                                       \
        for (int i_ = 0; i_ < 4; ++i_)                                          \
            _Pragma("unroll")                                                   \
            for (int j_ = 0; j_ < 4; ++j_)                                      \
                acc[i_][j_] = __builtin_amdgcn_mfma_i32_16x16x64_i8(            \
                    af[i_], bfr_[j_], acc[i_][j_], 0, 0, 0);                    \
    } while (0)

    i32x4 afA[4], afB[4];

    // prologue: stage 0 into buf0, weights 0 into afA
    STAGE(0, 0);
    LOADW(afA, 0);
    __syncthreads();   // vmcnt(0): stage-0 data landed; also covers Sa_l/Wsum_l

    for (int t = 0; t < 8; ++t) {
        const int st1 = t * 2 + 1;
        // even phase: prefetch odd stage, compute even stage
        STAGE(1, st1);
        LOADW(afB, st1);
        COMPUTE(0, afA);
        __syncthreads(); // drains prefetch; all reads of buf0 done
        // odd phase: prefetch next even stage, compute odd stage
        STAGE(0, st1 + 1);
        LOADW(afA, st1 + 1);
        COMPUTE(1, afB);
        __syncthreads(); // drains prefetch; all reads of buf1 done
    }
    // tail: stages 16,17
    STAGE(1, 17);
    LOADW(afB, 17);
    COMPUTE(0, afA);
    __syncthreads();
    COMPUTE(1, afB);

#undef STAGE
#undef LOADW
#undef COMPUTE

    // ---- epilogue: D[row=o][col=m]; col=lane&15, row=quad*4+reg ----
    const int hh = h0 + wm;
    int sa_j[4];
#pragma unroll
    for (int j = 0; j < 4; ++j) {
        const int w = j * 16 + lrow;
        sa_j[j] = (w < HW) ? Sa_l[wm][w] : 0;
    }
#pragma unroll
    for (int i = 0; i < 4; i++) {
        const int obase = wo * 64 + i * 16 + quad * 4;   // o - o_blk
#pragma unroll
        for (int rg = 0; rg < 4; ++rg) {
            const int oo = obase + rg;
            const int o = o_blk + oo;
            const int wsum = Wsum_l[oo];
            const float bs = bias[o];
#pragma unroll
            for (int j = 0; j < 4; ++j) {
                const int w = j * 16 + lrow;
                if (w < HW) {
                    int tot = acc[i][j][rg] + 128 * (sa_j[j] + wsum) + 18874368;
                    out[(((size_t)b * O_CH + o) * HW + hh) * HW + w] = (float)tot + bs;
                }
            }
        }
    }
}

extern "C" void kernel_launch(void* const* d_in, const int* in_sizes, int n_in,
                              void* d_out, int out_size, void* d_ws, size_t ws_size,
                              hipStream_t stream) {
    const float* x     = (const float*)d_in[0];
    const float* pcilt = (const float*)d_in[1];
    const float* bias  = (const float*)d_in[2];
    float* out = (float*)d_out;

    u8* ws = (u8*)d_ws;
    u8*  xq    = ws + XQ_OFF;
    u8*  Bw    = ws + BW_OFF;
    int* Tc    = (int*)(ws + TC_OFF);
    int* Wpart = (int*)(ws + WP_OFF);

    prep<<<PH * B_N + 288, 256, 0, stream>>>(x, pcilt, xq, Bw, Tc, Wpart);
    conv_mfma<<<dim3(O_CH / 128, HW / 2, B_N), dim3(256), 0, stream>>>(xq, Bw, Tc, Wpart, bias, out);
}